// Round 14
// baseline (805.413 us; speedup 1.0000x reference)
//
#include <hip/hip_runtime.h>
#include <hip/hip_bf16.h>

typedef __hip_bfloat16 bf16;
typedef unsigned short u16;
typedef __attribute__((ext_vector_type(8))) short short8;
typedef __attribute__((ext_vector_type(4))) float f32x4;

#define Bb   128
#define MEMm 40
#define REP  3

__device__ __forceinline__ float LD(const void* p, size_t i, int f32) {
    return f32 ? ((const float*)p)[i] : __bfloat162float(((const bf16*)p)[i]);
}
__device__ __forceinline__ float S2F(short s) {
    u16 u = (u16)s;
    return __bfloat162float(*(bf16*)&u);
}
__device__ __forceinline__ u16 F2S(float v) {
    bf16 h = __float2bfloat16(v);
    return *(u16*)&h;
}
__device__ __forceinline__ int LDB(const void* p, int i, int isbyte) {
    return isbyte ? (int)((const unsigned char*)p)[i] : ((const int*)p)[i];
}

// MEASUREMENT ROUND: conv and attn bodies repeated REP x (idempotent);
// setup/tail single-pass. Numerics identical to round 13.

// fused setup. Units: [0,20) bias, [20,276) init_prevout, [276,6612) repack.
__global__ void setup_kernel(const void* __restrict__ x,
                             const void* __restrict__ src_mask,
                             const void* __restrict__ notdone,
                             const void* __restrict__ h0,
                             const void* __restrict__ mw,
                             const void* __restrict__ pw,
                             const void* __restrict__ ow,
                             int* __restrict__ flags,
                             float* __restrict__ biasb,
                             float* __restrict__ outb, size_t hoff,
                             u16* __restrict__ whi) {
    __shared__ int det[3];
    const int bid = blockIdx.x, t = threadIdx.x;
    if (t < 3) det[t] = 0;
    __syncthreads();
    {
        const bf16* xb = (const bf16*)x;
        int bad = 0;
        for (int i = t; i < 4096; i += 256) {
            float v = __bfloat162float(xb[2 * i]);   // even halves: garbage iff f32
            if (!(fabsf(v) < 1e4f)) bad = 1;
        }
        if (bad) atomicOr(&det[0], 1);
        int mb = 0;
        const unsigned* mi = (const unsigned*)src_mask;
        for (int i = t; i < 1280; i += 256) if (mi[i] > 1u) mb = 1;
        if (mb) atomicOr(&det[1], 1);
        int nb = 0;
        const unsigned* ni = (const unsigned*)notdone;
        for (int i = t; i < 32; i += 256) if (ni[i] > 1u) nb = 1;
        if (nb) atomicOr(&det[2], 1);
    }
    __syncthreads();
    const int isf32 = det[0], mbyte = det[1], ndbyte = det[2];
    if (bid == 0 && t < 3) flags[t] = det[t];

    if (bid < 20) {
        int idx = bid * 256 + t;
        if (idx >= Bb * MEMm) return;
        int b = idx / MEMm, m = idx - b * MEMm;
        float v;
        if (m == MEMm - 1) v = 3.0f;
        else {
            bool masked = (LDB(src_mask, b * MEMm + m + 1, mbyte) != 0) ||
                          (LDB(notdone, b, ndbyte) == 0);
            v = masked ? -1e9f : 0.f;
        }
        biasb[idx] = v;
    } else if (bid < 276) {
        int idx = (bid - 20) * 256 + t;      // < 65536
        int b = idx >> 9;
        float nd = (LDB(notdone, b, ndbyte) != 0) ? 1.f : 0.f;
        size_t e = (size_t)idx * 8;
        float v[8];
        if (isf32) {
            const float* hp = (const float*)h0 + hoff + e;
            f32x4 p0 = *(const f32x4*)hp, p1 = *(const f32x4*)(hp + 4);
#pragma unroll
            for (int j = 0; j < 4; ++j) { v[j] = p0[j]; v[4 + j] = p1[j]; }
        } else {
            short8 s = *(const short8*)((const bf16*)h0 + hoff + e);
#pragma unroll
            for (int j = 0; j < 8; ++j) v[j] = S2F(s[j]);
        }
#pragma unroll
        for (int j = 0; j < 8; ++j) outb[e + j] = v[j] * nd;
    } else {
        int gi = (bid - 276) * 256 + t;
        if (gi >= 1622016) return;
        int layer = (gi >= 811008) ? 1 : 0;
        int i = gi - layer * 811008;
        float v;
        if (i < 552960) {
            int blk = i >> 9, r = i & 511;
            int l = r >> 3, j = r & 7;
            int nn = blk & 1, b2 = blk >> 1;
            int s = b2 % 10, tk = b2 / 10;
            int kc = tk % 6, tap = tk / 6;
            int co = s * 32 + nn * 16 + (l & 15);
            int ci = kc * 32 + ((l >> 4) << 3) + j;
            v = LD(mw, (size_t)layer * 552960 + ((size_t)co * 192 + ci) * 9 + tap, isf32);
        } else if (i < 774144) {
            int j2 = i - 552960;
            int blk = j2 >> 9, r = j2 & 511;
            int l = r >> 3, j = r & 7;
            int nn = blk & 1, b2 = blk >> 1;
            int s = b2 % 6, tk = b2 / 6;
            int kc = tk & 3, tap = tk >> 2;
            int co = s * 32 + nn * 16 + (l & 15);
            int ci = kc * 32 + ((l >> 4) << 3) + j;
            v = LD(pw, (size_t)layer * 221184 + ((size_t)co * 128 + ci) * 9 + tap, isf32);
        } else {
            int j2 = i - 774144;
            int tap = j2 / 4096, r = j2 - tap * 4096, co = r / 64, ci = r - co * 64;
            v = LD(ow, (size_t)layer * 36864 + ((size_t)co * 64 + ci) * 9 + tap, isf32);
        }
        whi[gi] = F2S(v);
    }
}

// ---------------------------------------------------------------- MFMA conv (x3)
struct ConvArgs {
    const void *x; const float *prev_out; const void *h0; const void *notdone;
    const u16 *WhiA, *WhiB;          // fragment-order regions (bf16)
    const void *biasA, *biasB;
    float *OutA, *OutB;              // [B][Cout][64]
    long long boffA, boffB;
    size_t hoff;
    int KciA, KciB, CoutA, CoutB, ntA, NMB;
};

__global__ __launch_bounds__(256) void conv_mfma_kernel(ConvArgs g,
                                                        const int* __restrict__ flags) {
    __shared__ __align__(16) u16 Alds[2][2600];   // [bpair][row*40+ci], row 64 = zeros
    const int t = threadIdx.x, w = t >> 6, lane = t & 63;
    const int bpair = w >> 1, half = w & 1;
    const int bx = blockIdx.x;
    const int mblk = bx % g.NMB, strip = bx / g.NMB;   // strip in [0,16)
    const bool isA = (strip < g.ntA);
    const u16* Whi = isA ? g.WhiA : g.WhiB;
    const int Kci  = isA ? g.KciA : g.KciB;
    const int CoutT= isA ? g.CoutA : g.CoutB;
    float* Out     = isA ? g.OutA : g.OutB;
    const void* bias = isA ? g.biasA : g.biasB;
    const long long boff = isA ? g.boffA : g.boffB;
    const int s = isA ? strip : strip - g.ntA;         // type-local 32-co strip
    const int b = mblk * 2 + bpair;
    const int kcN = Kci >> 5;
    const int CoutT32 = CoutT >> 5;
    const int NITER = kcN * 9;
    const int isf32 = flags[0];
    const float nd = (LDB(g.notdone, b, flags[2]) != 0) ? 1.f : 0.f;

    if (half == 0 && lane < 40) Alds[bpair][2560 + lane] = 0;

    auto wbase = [&](int it) -> size_t {
        int kc = it / 9, tap = it - kc * 9;
        return ((size_t)((tap * kcN + kc) * CoutT32 + s) * 2 + half) * 512 + (size_t)lane * 8;
    };

#pragma unroll 1
    for (int rep = 0; rep < REP; ++rep) {
        asm volatile("" ::: "memory");
        f32x4 acc[4];
#pragma unroll
        for (int i = 0; i < 4; ++i) { f32x4 z = {0.f, 0.f, 0.f, 0.f}; acc[i] = z; }

        short8 wcur = *(const short8*)(Whi + wbase(0));
        short8 wnext = wcur;

        for (int it = 0; it < NITER; ++it) {
            const int kc = it / 9, tap = it - kc * 9;
            if (it + 1 < NITER) wnext = *(const short8*)(Whi + wbase(it + 1));
            if (tap == 0) {
                __syncthreads();   // WAR: prior kc's (or prior rep's) A reads complete
                const int px = lane;
                const int c0i = half * 16;
                const int cbase = kc * 32;
                short8 hA, hB;
#pragma unroll
                for (int cl2 = 0; cl2 < 16; ++cl2) {
                    int c = cbase + c0i + cl2;
                    float v;
                    if (c < 64) {
                        size_t o = (size_t)b * 4096 + (size_t)c * 64 + px;
                        v = isf32 ? ((const float*)g.x)[o] : S2F(((const short*)g.x)[o]);
                    } else if (c < 128) {
                        v = g.prev_out[(size_t)b * 4096 + (size_t)(c - 64) * 64 + px];
                    } else {
                        size_t o = g.hoff + (size_t)b * 4096 + (size_t)(c - 128) * 64 + px;
                        v = (isf32 ? ((const float*)g.h0)[o] : S2F(((const short*)g.h0)[o])) * nd;
                    }
                    u16 hh = F2S(v);
                    if (cl2 < 8) hA[cl2] = (short)hh;
                    else         hB[cl2 - 8] = (short)hh;
                }
                *(short8*)&Alds[bpair][px * 40 + c0i]     = hA;
                *(short8*)&Alds[bpair][px * 40 + c0i + 8] = hB;
                __syncthreads();   // RAW: A visible to both waves of the pair
            }
            const int dy = tap / 3 - 1, dx = tap % 3 - 1;
            const int q8 = (lane >> 4) * 8;
            const int ml = lane & 15;
            short8 aH[4];
#pragma unroll
            for (int mt = 0; mt < 4; ++mt) {
                int px = mt * 16 + ml;
                int yy = (px >> 3) + dy, xx = (px & 7) + dx;
                int row = ((unsigned)yy < 8u && (unsigned)xx < 8u) ? yy * 8 + xx : 64;
                aH[mt] = *(const short8*)&Alds[bpair][row * 40 + q8];
            }
#pragma unroll
            for (int mt = 0; mt < 4; ++mt)
                acc[mt] = __builtin_amdgcn_mfma_f32_16x16x32_bf16(aH[mt], wcur, acc[mt], 0, 0, 0);
            wcur = wnext;
        }
        // epilogue: C layout col=lane&15, row=(lane>>4)*4+reg
        const int q = lane >> 4, ml = lane & 15;
        {
            int co = s * 32 + half * 16 + ml;
            float bv = LD(bias, (size_t)boff + co, isf32);
#pragma unroll
            for (int mt = 0; mt < 4; ++mt) {
                f32x4 v = acc[mt];
                v[0] += bv; v[1] += bv; v[2] += bv; v[3] += bv;
                *(f32x4*)&Out[((size_t)b * CoutT + co) * 64 + mt * 16 + q * 4] = v;
            }
        }
    }
}

// ---------------------------------------------------------------- attention (x3)
__global__ __launch_bounds__(256) void attn_kernel(
    const float* __restrict__ kqv,
    const void* __restrict__ k0,
    const void* __restrict__ v0,
    const void* __restrict__ pw,
    const void* __restrict__ pb,
    const float* __restrict__ biasb,
    const int* __restrict__ flags,
    u16* __restrict__ ahi,
    size_t kvoff, size_t pwoff, size_t pboff) {
    __shared__ float qv[512], kl[512], vl[512], sc[40], wexp[40];
    __shared__ float accbuf[4][512];
    const int t = threadIdx.x;
    const int isf32 = flags[0];
    const int b = blockIdx.x >> 3, h = blockIdx.x & 7;
    const size_t kqb = (size_t)b * 192 * 64;
    const int wid = t >> 6, lane = t & 63;
    const int d0 = lane * 8;
    const size_t kvbase = kvoff + ((size_t)(b * 8 + h)) * (size_t)(40 * 512);

#pragma unroll 1
    for (int rep = 0; rep < REP; ++rep) {
        asm volatile("" ::: "memory");
        for (int d = t; d < 512; d += 256) {
            int hd = d >> 6, ss = d & 63;
            qv[d] = kqv[kqb + (h * 24 + 8 + hd) * 64 + ss] * 0.044194173824159216f;
            kl[d] = kqv[kqb + (h * 24 + 0 + hd) * 64 + ss];
            vl[d] = kqv[kqb + (h * 24 + 16 + hd) * 64 + ss];
        }
        __syncthreads();

        float q8[8];
#pragma unroll
        for (int j = 0; j < 8; ++j) q8[j] = qv[d0 + j];

        if (!isf32) {
            const bf16* kp = (const bf16*)k0;
            const bf16* pp = (const bf16*)pw;
            const bf16* vp = (const bf16*)v0;
            short8 kr[10], pr[10];
#pragma unroll
            for (int i = 0; i < 10; ++i) {
                int m = wid + i * 4;
                pr[i] = *(const short8*)(pp + pwoff + (size_t)m * 4096 + h * 512 + d0);
                if (m < 39)
                    kr[i] = *(const short8*)(kp + kvbase + (size_t)(m + 1) * 512 + d0);
            }
#pragma unroll
            for (int i = 0; i < 10; ++i) {
                int m = wid + i * 4;
                float p = 0.f;
                if (m < 39) {
#pragma unroll
                    for (int j = 0; j < 8; ++j)
                        p += q8[j] * (S2F(kr[i][j]) + S2F(pr[i][j]));
                } else {
#pragma unroll
                    for (int j = 0; j < 8; ++j)
                        p += q8[j] * (kl[d0 + j] + S2F(pr[i][j]));
                }
#pragma unroll
                for (int off = 32; off > 0; off >>= 1) p += __shfl_down(p, off, 64);
                if (lane == 0)
                    sc[m] = p + biasb[b * 40 + m] + LD(pb, pboff + m * 8 + h, 0);
            }
            short8 vr[10];
#pragma unroll
            for (int i = 0; i < 10; ++i) {
                int m = wid + i * 4;
                if (m < 39)
                    vr[i] = *(const short8*)(vp + kvbase + (size_t)(m + 1) * 512 + d0);
            }
            __syncthreads();
            float mx = -1e30f;
            for (int m = 0; m < 40; ++m) mx = fmaxf(mx, sc[m]);
            if (t < 40) wexp[t] = __expf(sc[t] - mx);
            __syncthreads();
            float sum = 0.f;
            for (int m = 0; m < 40; ++m) sum += wexp[m];
            float rs = 1.f / sum;
            float acc8[8];
#pragma unroll
            for (int j = 0; j < 8; ++j) acc8[j] = 0.f;
#pragma unroll
            for (int i = 0; i < 10; ++i) {
                int m = wid + i * 4;
                float wgt = wexp[m];
                if (m < 39) {
#pragma unroll
                    for (int j = 0; j < 8; ++j) acc8[j] += wgt * S2F(vr[i][j]);
                } else {
#pragma unroll
                    for (int j = 0; j < 8; ++j) acc8[j] += wgt * vl[d0 + j];
                }
            }
#pragma unroll
            for (int j = 0; j < 8; ++j) accbuf[wid][d0 + j] = acc8[j];
            __syncthreads();
            for (int d = t; d < 512; d += 256) {
                float acc = (accbuf[0][d] + accbuf[1][d]) + (accbuf[2][d] + accbuf[3][d]);
                acc *= rs;
                int ch = h * 8 + (d >> 6), px = d & 63;
                ahi[(size_t)b * 4096 + px * 64 + ch] = F2S(acc);
            }
        } else {
            for (int m = wid; m < 40; m += 4) {
                float kc[8];
                if (m < 39) {
                    const float* kp = (const float*)k0 + kvbase + (size_t)(m + 1) * 512 + d0;
                    f32x4 p0 = *(const f32x4*)kp, p1 = *(const f32x4*)(kp + 4);
#pragma unroll
                    for (int j = 0; j < 4; ++j) { kc[j] = p0[j]; kc[4 + j] = p1[j]; }
                } else {
#pragma unroll
                    for (int j = 0; j < 8; ++j) kc[j] = kl[d0 + j];
                }
                const float* pp = (const float*)pw + pwoff + (size_t)m * 4096 + h * 512 + d0;
                f32x4 p0 = *(const f32x4*)pp, p1 = *(const f32x4*)(pp + 4);
#pragma unroll
                for (int j = 0; j < 4; ++j) { kc[j] += p0[j]; kc[4 + j] += p1[j]; }
                float p = 0.f;
#pragma unroll
                for (int j = 0; j < 8; ++j) p += q8[j] * kc[j];
#pragma unroll
                for (int off = 32; off > 0; off >>= 1) p += __shfl_down(p, off, 64);
                if (lane == 0)
                    sc[m] = p + biasb[b * 40 + m] + LD(pb, pboff + m * 8 + h, 1);
            }
            __syncthreads();
            float mx = -1e30f;
            for (int m = 0; m < 40; ++m) mx = fmaxf(mx, sc[m]);
            if (t < 40) wexp[t] = __expf(sc[t] - mx);
            __syncthreads();
            float sum = 0.f;
            for (int m = 0; m < 40; ++m) sum += wexp[m];
            float rs = 1.f / sum;
            float acc8[8];
#pragma unroll
            for (int j = 0; j < 8; ++j) acc8[j] = 0.f;
            for (int m = wid; m < 40; m += 4) {
                float wgt = wexp[m];
                if (m < 39) {
                    const float* vp = (const float*)v0 + kvbase + (size_t)(m + 1) * 512 + d0;
                    f32x4 p0 = *(const f32x4*)vp, p1 = *(const f32x4*)(vp + 4);
#pragma unroll
                    for (int j = 0; j < 4; ++j) { acc8[j] += wgt * p0[j]; acc8[4 + j] += wgt * p1[j]; }
                } else {
#pragma unroll
                    for (int j = 0; j < 8; ++j) acc8[j] += wgt * vl[d0 + j];
                }
            }
#pragma unroll
            for (int j = 0; j < 8; ++j) accbuf[wid][d0 + j] = acc8[j];
            __syncthreads();
            for (int d = t; d < 512; d += 256) {
                float acc = (accbuf[0][d] + accbuf[1][d]) + (accbuf[2][d] + accbuf[3][d]);
                acc *= rs;
                int ch = h * 8 + (d >> 6), px = d & 63;
                ahi[(size_t)b * 4096 + px * 64 + ch] = F2S(acc);
            }
        }
        __syncthreads();   // rep boundary guard (qv/kl/vl/sc/wexp/accbuf WAR)
    }
}

// ---------------------------------------------------------------- tail
// fused out-conv (pure bf16 MFMA, OLD W layout) + residual + LN + LSTM.
__global__ __launch_bounds__(256) void tail_kernel(
    const u16* __restrict__ ahi,
    const u16* __restrict__ whi,
    const void* __restrict__ outb_bias,
    const void* __restrict__ x,
    const float* __restrict__ gates,
    const void* __restrict__ c0,
    const void* __restrict__ notdone,
    const void* __restrict__ lnw, const void* __restrict__ lnb,
    const int* __restrict__ flags,
    float* __restrict__ out_buf, void* __restrict__ dout, int write_out,
    long long boff, size_t coff, size_t lnoff) {
    __shared__ __align__(16) u16 Ald[2][2600];       // [kc][px*40+cl], row 64 zeros
    __shared__ __align__(16) u16 Wl[2][2560];        // [par][co*40+ci]
    __shared__ float red[8], stats[2];
    const int t = threadIdx.x, w = t >> 6, lane = t & 63;
    const int b = blockIdx.x;
    const int isf32 = flags[0], ndbyte = flags[2];

    {
        int px = t >> 2, ci16 = (t & 3) * 16;
        int chunk = ci16 >> 5, cl = ci16 & 31;
        size_t o = ((size_t)b * 64 + px) * 64 + ci16;
        *(uint4*)&Ald[chunk][px * 40 + cl]     = *(const uint4*)(ahi + o);
        *(uint4*)&Ald[chunk][px * 40 + cl + 8] = *(const uint4*)(ahi + o + 8);
        if (t < 80) { int ch = t / 40, i = t % 40; Ald[ch][2560 + i] = 0; }
    }

    const int co_l = t >> 2, jj = t & 3;
    uint4 hv;
    auto issueW = [&](int it) {
        int kc = it / 9, tap = it - kc * 9;
        size_t o = ((size_t)(tap * 64 + co_l)) * 64 + kc * 32 + jj * 8;
        hv = *(const uint4*)(whi + o);
    };

    f32x4 acc[4];
#pragma unroll
    for (int i = 0; i < 4; ++i) { f32x4 z = {0.f, 0.f, 0.f, 0.f}; acc[i] = z; }

    issueW(0);
    for (int it = 0; it < 18; ++it) {
        const int kc = it / 9, tap = it - kc * 9;
        const int par = it & 1;
        *(uint4*)&Wl[par][co_l * 40 + jj * 8] = hv;
        __syncthreads();
        if (it + 1 < 18) issueW(it + 1);
        const int dy = tap / 3 - 1, dx = tap % 3 - 1;
        const int q8 = (lane >> 4) * 8;
        const int ml = lane & 15;
        short8 aH[4];
#pragma unroll
        for (int mt = 0; mt < 4; ++mt) {
            int px = mt * 16 + ml;
            int yy = (px >> 3) + dy, xx = (px & 7) + dx;
            int row = ((unsigned)yy < 8u && (unsigned)xx < 8u) ? yy * 8 + xx : 64;
            aH[mt] = *(const short8*)&Ald[kc][row * 40 + q8];
        }
        short8 bH = *(const short8*)&Wl[par][(w * 16 + ml) * 40 + q8];
#pragma unroll
        for (int mt = 0; mt < 4; ++mt)
            acc[mt] = __builtin_amdgcn_mfma_f32_16x16x32_bf16(aH[mt], bH, acc[mt], 0, 0, 0);
    }

    // epilogue: thread holds 16 values at co = w*16+(lane&15), px = mt*16+(lane>>4)*4+r
    const int q = lane >> 4, ml = lane & 15;
    const int co = w * 16 + ml;
    const size_t base = (size_t)b * 4096;
    float bv = LD(outb_bias, (size_t)boff + co, isf32);
    float vals[16];
    float sum = 0.f, sumsq = 0.f;
#pragma unroll
    for (int mt = 0; mt < 4; ++mt) {
        int px0 = mt * 16 + q * 4;
#pragma unroll
        for (int r = 0; r < 4; ++r) {
            float xv = LD(x, base + (size_t)co * 64 + px0 + r, isf32);
            float val = acc[mt][r] + bv + xv;
            vals[mt * 4 + r] = val; sum += val; sumsq += val * val;
        }
    }
#pragma unroll
    for (int off = 32; off > 0; off >>= 1) {
        sum   += __shfl_down(sum, off, 64);
        sumsq += __shfl_down(sumsq, off, 64);
    }
    if (lane == 0) { red[w] = sum; red[4 + w] = sumsq; }
    __syncthreads();
    if (t == 0) {
        float ts = red[0] + red[1] + red[2] + red[3];
        float tq = red[4] + red[5] + red[6] + red[7];
        float mu = ts * (1.f / 4096.f);
        float var = tq * (1.f / 4096.f) - mu * mu;
        stats[0] = mu; stats[1] = rsqrtf(fmaxf(var, 0.f) + 1e-5f);
    }
    __syncthreads();
    const float mu = stats[0], rstd = stats[1];
    const float nd = (LDB(notdone, b, ndbyte) != 0) ? 1.f : 0.f;
    const size_t gbase = (size_t)b * 320 * 64;
#pragma unroll
    for (int mt = 0; mt < 4; ++mt) {
        int px0 = mt * 16 + q * 4;
        size_t i0 = (size_t)co * 64 + px0;
        f32x4 gi4 = *(const f32x4*)&gates[gbase + (size_t)(co      ) * 64 + px0];
        f32x4 gf4 = *(const f32x4*)&gates[gbase + (size_t)(co +  64) * 64 + px0];
        f32x4 go4 = *(const f32x4*)&gates[gbase + (size_t)(co + 128) * 64 + px0];
        f32x4 gg4 = *(const f32x4*)&gates[gbase + (size_t)(co + 192) * 64 + px0];
        f32x4 ga4 = *(const f32x4*)&gates[gbase + (size_t)(co + 256) * 64 + px0];
        f32x4 ov;
#pragma unroll
        for (int r = 0; r < 4; ++r) {
            size_t i = i0 + r;
            float aon = (vals[mt * 4 + r] - mu) * rstd * LD(lnw, lnoff + i, isf32)
                        + LD(lnb, lnoff + i, isf32);
            float gi = 1.f / (1.f + __expf(-gi4[r]));
            float gf = 1.f / (1.f + __expf(-gf4[r]));
            float go = 1.f / (1.f + __expf(-go4[r]));
            float gg = tanhf(gg4[r]);
            float ga = 1.f / (1.f + __expf(-ga4[r]));
            float cc = LD(c0, coff + base + i, isf32) * nd;
            float cn = gf * cc + gi * gg + ga * tanhf(aon);
            float o  = go * tanhf(cn);
            ov[r] = o;
            if (write_out) {
                if (isf32) ((float*)dout)[base + i] = o;
                else       ((bf16*)dout)[base + i] = __float2bfloat16(o);
            }
        }
        *(f32x4*)&out_buf[base + i0] = ov;
    }
}

extern "C" void kernel_launch(void* const* d_in, const int* in_sizes, int n_in,
                              void* d_out, int out_size, void* d_ws, size_t ws_size,
                              hipStream_t stream) {
    const void* x      = d_in[0];
    const void* h0     = d_in[1];
    const void* c0     = d_in[2];
    const void* k0     = d_in[3];
    const void* v0     = d_in[4];
    const void* src_mask = d_in[5];
    const void* notdone  = d_in[6];
    const void* main_w = d_in[7];
    const void* main_b = d_in[8];
    const void* proj_w = d_in[9];
    const void* proj_b = d_in[10];
    const void* out_w  = d_in[11];
    const void* out_b  = d_in[12];
    const void* ln_w   = d_in[13];
    const void* ln_b   = d_in[14];
    const void* pos_w  = d_in[15];
    const void* pos_b  = d_in[16];

    float* wsf = (float*)d_ws;
    int*   flags    = (int*)d_ws;
    float* bias_buf = wsf + 8;
    float* out_buf  = wsf + 8192;              // 524288 f
    float* gates_buf= wsf + 532480;            // 2621440 f
    float* kqv_buf  = wsf + 3153920;           // 1572864 f
    u16* attn_hi    = (u16*)(wsf + 4726784);   // 524288 u16
    u16* wr_hi      = (u16*)(wsf + 4988928);   // 1622016 u16 (both layers)
                                               // end @ 5799936 f = 23.2 MB

    setup_kernel<<<6612, 256, 0, stream>>>(x, src_mask, notdone, h0,
                                           main_w, proj_w, out_w, flags,
                                           bias_buf, out_buf, (size_t)524288,
                                           wr_hi);
    for (int n = 0; n < 2; ++n) {
        const size_t wb = (size_t)n * 811008;
        ConvArgs ga;
        ga.x = x; ga.prev_out = out_buf; ga.h0 = h0; ga.notdone = notdone;
        ga.hoff = (size_t)n * 524288;
        ga.WhiA = wr_hi + wb;          ga.KciA = 192; ga.CoutA = 320;
        ga.WhiB = wr_hi + wb + 552960; ga.KciB = 128; ga.CoutB = 192;
        ga.biasA = main_b; ga.boffA = (long long)n * 320; ga.OutA = gates_buf;
        ga.biasB = proj_b; ga.boffB = (long long)n * 192; ga.OutB = kqv_buf;
        ga.ntA = 10; ga.NMB = 64;
        conv_mfma_kernel<<<1024, 256, 0, stream>>>(ga, flags);

        attn_kernel<<<1024, 256, 0, stream>>>(
            kqv_buf, k0, v0, pos_w, pos_b, bias_buf, flags, attn_hi,
            (size_t)n * 20971520, (size_t)n * 163840, (size_t)n * 320);

        tail_kernel<<<128, 256, 0, stream>>>(
            attn_hi, wr_hi + wb + 774144,
            out_b, x, gates_buf, c0, notdone, ln_w, ln_b, flags,
            out_buf, d_out, (n == 1) ? 1 : 0,
            (long long)n * 64, (size_t)n * 524288, (size_t)n * 4096);
    }
}

// Round 15
// 574.665 us; speedup vs baseline: 1.4015x; 1.4015x over previous
//
#include <hip/hip_runtime.h>
#include <hip/hip_bf16.h>

typedef __hip_bfloat16 bf16;
typedef unsigned short u16;
typedef __attribute__((ext_vector_type(8))) short short8;
typedef __attribute__((ext_vector_type(4))) float f32x4;

#define Bb   128
#define MEMm 40

__device__ __forceinline__ float LD(const void* p, size_t i, int f32) {
    return f32 ? ((const float*)p)[i] : __bfloat162float(((const bf16*)p)[i]);
}
__device__ __forceinline__ float S2F(short s) {
    u16 u = (u16)s;
    return __bfloat162float(*(bf16*)&u);
}
__device__ __forceinline__ u16 F2S(float v) {
    bf16 h = __float2bfloat16(v);
    return *(u16*)&h;
}
__device__ __forceinline__ int LDB(const void* p, int i, int isbyte) {
    return isbyte ? (int)((const unsigned char*)p)[i] : ((const int*)p)[i];
}

// fused setup. Units: [0,20) bias, [20,276) init_prevout, [276,6612) repack.
__global__ void setup_kernel(const void* __restrict__ x,
                             const void* __restrict__ src_mask,
                             const void* __restrict__ notdone,
                             const void* __restrict__ h0,
                             const void* __restrict__ mw,
                             const void* __restrict__ pw,
                             const void* __restrict__ ow,
                             int* __restrict__ flags,
                             float* __restrict__ biasb,
                             float* __restrict__ outb, size_t hoff,
                             u16* __restrict__ whi) {
    __shared__ int det[3];
    const int bid = blockIdx.x, t = threadIdx.x;
    if (t < 3) det[t] = 0;
    __syncthreads();
    {
        const bf16* xb = (const bf16*)x;
        int bad = 0;
        for (int i = t; i < 4096; i += 256) {
            float v = __bfloat162float(xb[2 * i]);   // even halves: garbage iff f32
            if (!(fabsf(v) < 1e4f)) bad = 1;
        }
        if (bad) atomicOr(&det[0], 1);
        int mb = 0;
        const unsigned* mi = (const unsigned*)src_mask;
        for (int i = t; i < 1280; i += 256) if (mi[i] > 1u) mb = 1;
        if (mb) atomicOr(&det[1], 1);
        int nb = 0;
        const unsigned* ni = (const unsigned*)notdone;
        for (int i = t; i < 32; i += 256) if (ni[i] > 1u) nb = 1;
        if (nb) atomicOr(&det[2], 1);
    }
    __syncthreads();
    const int isf32 = det[0], mbyte = det[1], ndbyte = det[2];
    if (bid == 0 && t < 3) flags[t] = det[t];

    if (bid < 20) {
        int idx = bid * 256 + t;
        if (idx >= Bb * MEMm) return;
        int b = idx / MEMm, m = idx - b * MEMm;
        float v;
        if (m == MEMm - 1) v = 3.0f;
        else {
            bool masked = (LDB(src_mask, b * MEMm + m + 1, mbyte) != 0) ||
                          (LDB(notdone, b, ndbyte) == 0);
            v = masked ? -1e9f : 0.f;
        }
        biasb[idx] = v;
    } else if (bid < 276) {
        int idx = (bid - 20) * 256 + t;      // < 65536
        int b = idx >> 9;
        float nd = (LDB(notdone, b, ndbyte) != 0) ? 1.f : 0.f;
        size_t e = (size_t)idx * 8;
        float v[8];
        if (isf32) {
            const float* hp = (const float*)h0 + hoff + e;
            f32x4 p0 = *(const f32x4*)hp, p1 = *(const f32x4*)(hp + 4);
#pragma unroll
            for (int j = 0; j < 4; ++j) { v[j] = p0[j]; v[4 + j] = p1[j]; }
        } else {
            short8 s = *(const short8*)((const bf16*)h0 + hoff + e);
#pragma unroll
            for (int j = 0; j < 8; ++j) v[j] = S2F(s[j]);
        }
#pragma unroll
        for (int j = 0; j < 8; ++j) outb[e + j] = v[j] * nd;
    } else {
        int gi = (bid - 276) * 256 + t;
        if (gi >= 1622016) return;
        int layer = (gi >= 811008) ? 1 : 0;
        int i = gi - layer * 811008;
        float v;
        if (i < 552960) {
            int blk = i >> 9, r = i & 511;
            int l = r >> 3, j = r & 7;
            int nn = blk & 1, b2 = blk >> 1;
            int s = b2 % 10, tk = b2 / 10;
            int kc = tk % 6, tap = tk / 6;
            int co = s * 32 + nn * 16 + (l & 15);
            int ci = kc * 32 + ((l >> 4) << 3) + j;
            v = LD(mw, (size_t)layer * 552960 + ((size_t)co * 192 + ci) * 9 + tap, isf32);
        } else if (i < 774144) {
            int j2 = i - 552960;
            int blk = j2 >> 9, r = j2 & 511;
            int l = r >> 3, j = r & 7;
            int nn = blk & 1, b2 = blk >> 1;
            int s = b2 % 6, tk = b2 / 6;
            int kc = tk & 3, tap = tk >> 2;
            int co = s * 32 + nn * 16 + (l & 15);
            int ci = kc * 32 + ((l >> 4) << 3) + j;
            v = LD(pw, (size_t)layer * 221184 + ((size_t)co * 128 + ci) * 9 + tap, isf32);
        } else {
            int j2 = i - 774144;
            int tap = j2 / 4096, r = j2 - tap * 4096, co = r / 64, ci = r - co * 64;
            v = LD(ow, (size_t)layer * 36864 + ((size_t)co * 64 + ci) * 9 + tap, isf32);
        }
        whi[gi] = F2S(v);
    }
}

// ---------------------------------------------------------------- MFMA conv
// 9-tap implicit GEMM, pure bf16 operands (f32 accumulate). 1 MFMA per
// fragment pair. block: 4 waves = 2 batches x one 32-co strip. Grid 1024.
struct ConvArgs {
    const void *x; const float *prev_out; const void *h0; const void *notdone;
    const u16 *WhiA, *WhiB;          // fragment-order regions (bf16)
    const void *biasA, *biasB;
    float *OutA, *OutB;              // [B][Cout][64]
    long long boffA, boffB;
    size_t hoff;
    int KciA, KciB, CoutA, CoutB, ntA, NMB;
};

__global__ __launch_bounds__(256) void conv_mfma_kernel(ConvArgs g,
                                                        const int* __restrict__ flags) {
    __shared__ __align__(16) u16 Alds[2][2600];   // [bpair][row*40+ci], row 64 = zeros
    const int t = threadIdx.x, w = t >> 6, lane = t & 63;
    const int bpair = w >> 1, half = w & 1;
    const int bx = blockIdx.x;
    const int mblk = bx % g.NMB, strip = bx / g.NMB;   // strip in [0,16)
    const bool isA = (strip < g.ntA);
    const u16* Whi = isA ? g.WhiA : g.WhiB;
    const int Kci  = isA ? g.KciA : g.KciB;
    const int CoutT= isA ? g.CoutA : g.CoutB;
    float* Out     = isA ? g.OutA : g.OutB;
    const void* bias = isA ? g.biasA : g.biasB;
    const long long boff = isA ? g.boffA : g.boffB;
    const int s = isA ? strip : strip - g.ntA;         // type-local 32-co strip
    const int b = mblk * 2 + bpair;
    const int kcN = Kci >> 5;
    const int CoutT32 = CoutT >> 5;
    const int NITER = kcN * 9;
    const int isf32 = flags[0];
    const float nd = (LDB(g.notdone, b, flags[2]) != 0) ? 1.f : 0.f;

    if (half == 0 && lane < 40) Alds[bpair][2560 + lane] = 0;

    f32x4 acc[4];
#pragma unroll
    for (int i = 0; i < 4; ++i) { f32x4 z = {0.f, 0.f, 0.f, 0.f}; acc[i] = z; }

    auto wbase = [&](int it) -> size_t {
        int kc = it / 9, tap = it - kc * 9;
        return ((size_t)((tap * kcN + kc) * CoutT32 + s) * 2 + half) * 512 + (size_t)lane * 8;
    };

    short8 wcur = *(const short8*)(Whi + wbase(0));
    short8 wnext = wcur;

    for (int it = 0; it < NITER; ++it) {
        const int kc = it / 9, tap = it - kc * 9;
        if (it + 1 < NITER) wnext = *(const short8*)(Whi + wbase(it + 1));
        if (tap == 0) {
            __syncthreads();   // WAR: prior kc's A reads complete
            const int px = lane;
            const int c0i = half * 16;
            const int cbase = kc * 32;
            short8 hA, hB;
#pragma unroll
            for (int cl2 = 0; cl2 < 16; ++cl2) {
                int c = cbase + c0i + cl2;
                float v;
                if (c < 64) {
                    size_t o = (size_t)b * 4096 + (size_t)c * 64 + px;
                    v = isf32 ? ((const float*)g.x)[o] : S2F(((const short*)g.x)[o]);
                } else if (c < 128) {
                    v = g.prev_out[(size_t)b * 4096 + (size_t)(c - 64) * 64 + px];
                } else {
                    size_t o = g.hoff + (size_t)b * 4096 + (size_t)(c - 128) * 64 + px;
                    v = (isf32 ? ((const float*)g.h0)[o] : S2F(((const short*)g.h0)[o])) * nd;
                }
                u16 hh = F2S(v);
                if (cl2 < 8) hA[cl2] = (short)hh;
                else         hB[cl2 - 8] = (short)hh;
            }
            *(short8*)&Alds[bpair][px * 40 + c0i]     = hA;
            *(short8*)&Alds[bpair][px * 40 + c0i + 8] = hB;
            __syncthreads();   // RAW: A visible to both waves of the pair
        }
        const int dy = tap / 3 - 1, dx = tap % 3 - 1;
        const int q8 = (lane >> 4) * 8;
        const int ml = lane & 15;
        short8 aH[4];
#pragma unroll
        for (int mt = 0; mt < 4; ++mt) {
            int px = mt * 16 + ml;
            int yy = (px >> 3) + dy, xx = (px & 7) + dx;
            int row = ((unsigned)yy < 8u && (unsigned)xx < 8u) ? yy * 8 + xx : 64;
            aH[mt] = *(const short8*)&Alds[bpair][row * 40 + q8];
        }
#pragma unroll
        for (int mt = 0; mt < 4; ++mt)
            acc[mt] = __builtin_amdgcn_mfma_f32_16x16x32_bf16(aH[mt], wcur, acc[mt], 0, 0, 0);
        wcur = wnext;
    }
    // epilogue: C layout col=lane&15, row=(lane>>4)*4+reg
    const int q = lane >> 4, ml = lane & 15;
    {
        int co = s * 32 + half * 16 + ml;
        float bv = LD(bias, (size_t)boff + co, isf32);
#pragma unroll
        for (int mt = 0; mt < 4; ++mt) {
            f32x4 v = acc[mt];
            v[0] += bv; v[1] += bv; v[2] += bv; v[3] += bv;
            *(f32x4*)&Out[((size_t)b * CoutT + co) * 64 + mt * 16 + q * 4] = v;
        }
    }
}

// ---------------------------------------------------------------- attention
// Wave-per-unit, barrier-free, zero LDS. One 64-lane wave handles one (b,h):
// q/k-last/v-last in registers; scores in 5-row pipelined batches with
// butterfly shfl reduce, score m parked in lane m; softmax fully in
// registers; PV in 5-row batches with shfl-broadcast weights.
__global__ __launch_bounds__(64) void attn_kernel(
    const float* __restrict__ kqv,
    const void* __restrict__ k0,
    const void* __restrict__ v0,
    const void* __restrict__ pw,
    const void* __restrict__ pb,
    const float* __restrict__ biasb,
    const int* __restrict__ flags,
    u16* __restrict__ ahi,
    size_t kvoff, size_t pwoff, size_t pboff) {
    const int lane = threadIdx.x & 63;
    const int u = blockIdx.x;
    const int b = u >> 3, h = u & 7;
    const int isf32 = flags[0];
    const size_t kqb = (size_t)b * 192 * 64;
    const int d0 = lane * 8;
    const int hd = d0 >> 6, ss = d0 & 63;
    const size_t kvbase = kvoff + ((size_t)(b * 8 + h)) * (size_t)(40 * 512);

    // q (scaled), k-last, v-last: straight to registers (f32 kqv buffer)
    float q8[8], kl8[8], vl8[8];
    {
        const float* qp = kqv + kqb + (size_t)(h * 24 + 8 + hd) * 64 + ss;
        const float* kp = kqv + kqb + (size_t)(h * 24 + 0 + hd) * 64 + ss;
        const float* vp = kqv + kqb + (size_t)(h * 24 + 16 + hd) * 64 + ss;
        f32x4 a0 = *(const f32x4*)qp, a1 = *(const f32x4*)(qp + 4);
        f32x4 b0 = *(const f32x4*)kp, b1 = *(const f32x4*)(kp + 4);
        f32x4 c0 = *(const f32x4*)vp, c1 = *(const f32x4*)(vp + 4);
#pragma unroll
        for (int j = 0; j < 4; ++j) {
            q8[j] = a0[j] * 0.044194173824159216f;
            q8[4 + j] = a1[j] * 0.044194173824159216f;
            kl8[j] = b0[j]; kl8[4 + j] = b1[j];
            vl8[j] = c0[j]; vl8[4 + j] = c1[j];
        }
    }

    float scv = 0.f;   // lane m (m<40) holds score m
    if (!isf32) {
        const bf16* kp = (const bf16*)k0;
        const bf16* pp = (const bf16*)pw;
#pragma unroll
        for (int base = 0; base < 40; base += 5) {
            short8 kr[5], pr[5];
#pragma unroll
            for (int i = 0; i < 5; ++i) {
                int m = base + i;
                pr[i] = *(const short8*)(pp + pwoff + (size_t)m * 4096 + h * 512 + d0);
                if (m < 39)
                    kr[i] = *(const short8*)(kp + kvbase + (size_t)(m + 1) * 512 + d0);
            }
#pragma unroll
            for (int i = 0; i < 5; ++i) {
                int m = base + i;
                float p = 0.f;
                if (m < 39) {
#pragma unroll
                    for (int j = 0; j < 8; ++j)
                        p += q8[j] * (S2F(kr[i][j]) + S2F(pr[i][j]));
                } else {
#pragma unroll
                    for (int j = 0; j < 8; ++j)
                        p += q8[j] * (kl8[j] + S2F(pr[i][j]));
                }
#pragma unroll
                for (int off = 32; off > 0; off >>= 1) p += __shfl_xor(p, off, 64);
                p += biasb[b * 40 + m] + LD(pb, pboff + m * 8 + h, 0);
                if (lane == m) scv = p;
            }
        }
    } else {
        const float* kp = (const float*)k0;
        const float* pp = (const float*)pw;
#pragma unroll 1
        for (int m = 0; m < 40; ++m) {
            float p = 0.f;
            const float* pr = pp + pwoff + (size_t)m * 4096 + h * 512 + d0;
            f32x4 p0 = *(const f32x4*)pr, p1 = *(const f32x4*)(pr + 4);
            if (m < 39) {
                const float* krp = kp + kvbase + (size_t)(m + 1) * 512 + d0;
                f32x4 k0v = *(const f32x4*)krp, k1v = *(const f32x4*)(krp + 4);
#pragma unroll
                for (int j = 0; j < 4; ++j) {
                    p += q8[j] * (k0v[j] + p0[j]);
                    p += q8[4 + j] * (k1v[j] + p1[j]);
                }
            } else {
#pragma unroll
                for (int j = 0; j < 4; ++j) {
                    p += q8[j] * (kl8[j] + p0[j]);
                    p += q8[4 + j] * (kl8[4 + j] + p1[j]);
                }
            }
#pragma unroll
            for (int off = 32; off > 0; off >>= 1) p += __shfl_xor(p, off, 64);
            p += biasb[b * 40 + m] + LD(pb, pboff + m * 8 + h, 1);
            if (lane == m) scv = p;
        }
    }

    // ---- in-register softmax over lanes 0..39
    float sv = (lane < 40) ? scv : -1e30f;
    float mx = sv;
#pragma unroll
    for (int off = 32; off > 0; off >>= 1) mx = fmaxf(mx, __shfl_xor(mx, off, 64));
    float wv = (lane < 40) ? __expf(scv - mx) : 0.f;
    float sum = wv;
#pragma unroll
    for (int off = 32; off > 0; off >>= 1) sum += __shfl_xor(sum, off, 64);
    const float rs = 1.f / sum;

    // ---- PV
    float acc8[8];
#pragma unroll
    for (int j = 0; j < 8; ++j) acc8[j] = 0.f;
    if (!isf32) {
        const bf16* vp = (const bf16*)v0;
#pragma unroll
        for (int base = 0; base < 40; base += 5) {
            short8 vr[5];
#pragma unroll
            for (int i = 0; i < 5; ++i) {
                int m = base + i;
                if (m < 39)
                    vr[i] = *(const short8*)(vp + kvbase + (size_t)(m + 1) * 512 + d0);
            }
#pragma unroll
            for (int i = 0; i < 5; ++i) {
                int m = base + i;
                float wgt = __shfl(wv, m, 64);
                if (m < 39) {
#pragma unroll
                    for (int j = 0; j < 8; ++j) acc8[j] += wgt * S2F(vr[i][j]);
                } else {
#pragma unroll
                    for (int j = 0; j < 8; ++j) acc8[j] += wgt * vl8[j];
                }
            }
        }
    } else {
        const float* vp = (const float*)v0;
#pragma unroll 1
        for (int m = 0; m < 40; ++m) {
            float wgt = __shfl(wv, m, 64);
            if (m < 39) {
                const float* vrp = vp + kvbase + (size_t)(m + 1) * 512 + d0;
                f32x4 v0v = *(const f32x4*)vrp, v1v = *(const f32x4*)(vrp + 4);
#pragma unroll
                for (int j = 0; j < 4; ++j) {
                    acc8[j] += wgt * v0v[j];
                    acc8[4 + j] += wgt * v1v[j];
                }
            } else {
#pragma unroll
                for (int j = 0; j < 8; ++j) acc8[j] += wgt * vl8[j];
            }
        }
    }

    // ---- store (out-conv A layout [b][px][ch]), bf16
    const int ch = h * 8 + hd;
#pragma unroll
    for (int j = 0; j < 8; ++j) {
        int px = ss + j;
        ahi[(size_t)b * 4096 + (size_t)px * 64 + ch] = F2S(acc8[j] * rs);
    }
}

// ---------------------------------------------------------------- tail
// fused out-conv (pure bf16 MFMA, OLD W layout) + residual + LN + LSTM.
__global__ __launch_bounds__(256) void tail_kernel(
    const u16* __restrict__ ahi,
    const u16* __restrict__ whi,
    const void* __restrict__ outb_bias,
    const void* __restrict__ x,
    const float* __restrict__ gates,
    const void* __restrict__ c0,
    const void* __restrict__ notdone,
    const void* __restrict__ lnw, const void* __restrict__ lnb,
    const int* __restrict__ flags,
    float* __restrict__ out_buf, void* __restrict__ dout, int write_out,
    long long boff, size_t coff, size_t lnoff) {
    __shared__ __align__(16) u16 Ald[2][2600];       // [kc][px*40+cl], row 64 zeros
    __shared__ __align__(16) u16 Wl[2][2560];        // [par][co*40+ci]
    __shared__ float red[8], stats[2];
    const int t = threadIdx.x, w = t >> 6, lane = t & 63;
    const int b = blockIdx.x;
    const int isf32 = flags[0], ndbyte = flags[2];

    {
        int px = t >> 2, ci16 = (t & 3) * 16;
        int chunk = ci16 >> 5, cl = ci16 & 31;
        size_t o = ((size_t)b * 64 + px) * 64 + ci16;
        *(uint4*)&Ald[chunk][px * 40 + cl]     = *(const uint4*)(ahi + o);
        *(uint4*)&Ald[chunk][px * 40 + cl + 8] = *(const uint4*)(ahi + o + 8);
        if (t < 80) { int ch = t / 40, i = t % 40; Ald[ch][2560 + i] = 0; }
    }

    const int co_l = t >> 2, jj = t & 3;
    uint4 hv;
    auto issueW = [&](int it) {
        int kc = it / 9, tap = it - kc * 9;
        size_t o = ((size_t)(tap * 64 + co_l)) * 64 + kc * 32 + jj * 8;
        hv = *(const uint4*)(whi + o);
    };

    f32x4 acc[4];
#pragma unroll
    for (int i = 0; i < 4; ++i) { f32x4 z = {0.f, 0.f, 0.f, 0.f}; acc[i] = z; }

    issueW(0);
    for (int it = 0; it < 18; ++it) {
        const int kc = it / 9, tap = it - kc * 9;
        const int par = it & 1;
        *(uint4*)&Wl[par][co_l * 40 + jj * 8] = hv;
        __syncthreads();
        if (it + 1 < 18) issueW(it + 1);
        const int dy = tap / 3 - 1, dx = tap % 3 - 1;
        const int q8 = (lane >> 4) * 8;
        const int ml = lane & 15;
        short8 aH[4];
#pragma unroll
        for (int mt = 0; mt < 4; ++mt) {
            int px = mt * 16 + ml;
            int yy = (px >> 3) + dy, xx = (px & 7) + dx;
            int row = ((unsigned)yy < 8u && (unsigned)xx < 8u) ? yy * 8 + xx : 64;
            aH[mt] = *(const short8*)&Ald[kc][row * 40 + q8];
        }
        short8 bH = *(const short8*)&Wl[par][(w * 16 + ml) * 40 + q8];
#pragma unroll
        for (int mt = 0; mt < 4; ++mt)
            acc[mt] = __builtin_amdgcn_mfma_f32_16x16x32_bf16(aH[mt], bH, acc[mt], 0, 0, 0);
    }

    // epilogue: thread holds 16 values at co = w*16+(lane&15), px = mt*16+(lane>>4)*4+r
    const int q = lane >> 4, ml = lane & 15;
    const int co = w * 16 + ml;
    const size_t base = (size_t)b * 4096;
    float bv = LD(outb_bias, (size_t)boff + co, isf32);
    float vals[16];
    float sum = 0.f, sumsq = 0.f;
#pragma unroll
    for (int mt = 0; mt < 4; ++mt) {
        int px0 = mt * 16 + q * 4;
#pragma unroll
        for (int r = 0; r < 4; ++r) {
            float xv = LD(x, base + (size_t)co * 64 + px0 + r, isf32);
            float val = acc[mt][r] + bv + xv;
            vals[mt * 4 + r] = val; sum += val; sumsq += val * val;
        }
    }
#pragma unroll
    for (int off = 32; off > 0; off >>= 1) {
        sum   += __shfl_down(sum, off, 64);
        sumsq += __shfl_down(sumsq, off, 64);
    }
    if (lane == 0) { red[w] = sum; red[4 + w] = sumsq; }
    __syncthreads();
    if (t == 0) {
        float ts = red[0] + red[1] + red[2] + red[3];
        float tq = red[4] + red[5] + red[6] + red[7];
        float mu = ts * (1.f / 4096.f);
        float var = tq * (1.f / 4096.f) - mu * mu;
        stats[0] = mu; stats[1] = rsqrtf(fmaxf(var, 0.f) + 1e-5f);
    }
    __syncthreads();
    const float mu = stats[0], rstd = stats[1];
    const float nd = (LDB(notdone, b, ndbyte) != 0) ? 1.f : 0.f;
    const size_t gbase = (size_t)b * 320 * 64;
#pragma unroll
    for (int mt = 0; mt < 4; ++mt) {
        int px0 = mt * 16 + q * 4;
        size_t i0 = (size_t)co * 64 + px0;
        f32x4 gi4 = *(const f32x4*)&gates[gbase + (size_t)(co      ) * 64 + px0];
        f32x4 gf4 = *(const f32x4*)&gates[gbase + (size_t)(co +  64) * 64 + px0];
        f32x4 go4 = *(const f32x4*)&gates[gbase + (size_t)(co + 128) * 64 + px0];
        f32x4 gg4 = *(const f32x4*)&gates[gbase + (size_t)(co + 192) * 64 + px0];
        f32x4 ga4 = *(const f32x4*)&gates[gbase + (size_t)(co + 256) * 64 + px0];
        f32x4 ov;
#pragma unroll
        for (int r = 0; r < 4; ++r) {
            size_t i = i0 + r;
            float aon = (vals[mt * 4 + r] - mu) * rstd * LD(lnw, lnoff + i, isf32)
                        + LD(lnb, lnoff + i, isf32);
            float gi = 1.f / (1.f + __expf(-gi4[r]));
            float gf = 1.f / (1.f + __expf(-gf4[r]));
            float go = 1.f / (1.f + __expf(-go4[r]));
            float gg = tanhf(gg4[r]);
            float ga = 1.f / (1.f + __expf(-ga4[r]));
            float cc = LD(c0, coff + base + i, isf32) * nd;
            float cn = gf * cc + gi * gg + ga * tanhf(aon);
            float o  = go * tanhf(cn);
            ov[r] = o;
            if (write_out) {
                if (isf32) ((float*)dout)[base + i] = o;
                else       ((bf16*)dout)[base + i] = __float2bfloat16(o);
            }
        }
        *(f32x4*)&out_buf[base + i0] = ov;
    }
}

extern "C" void kernel_launch(void* const* d_in, const int* in_sizes, int n_in,
                              void* d_out, int out_size, void* d_ws, size_t ws_size,
                              hipStream_t stream) {
    const void* x      = d_in[0];
    const void* h0     = d_in[1];
    const void* c0     = d_in[2];
    const void* k0     = d_in[3];
    const void* v0     = d_in[4];
    const void* src_mask = d_in[5];
    const void* notdone  = d_in[6];
    const void* main_w = d_in[7];
    const void* main_b = d_in[8];
    const void* proj_w = d_in[9];
    const void* proj_b = d_in[10];
    const void* out_w  = d_in[11];
    const void* out_b  = d_in[12];
    const void* ln_w   = d_in[13];
    const void* ln_b   = d_in[14];
    const void* pos_w  = d_in[15];
    const void* pos_b  = d_in[16];

    float* wsf = (float*)d_ws;
    int*   flags    = (int*)d_ws;
    float* bias_buf = wsf + 8;
    float* out_buf  = wsf + 8192;              // 524288 f
    float* gates_buf= wsf + 532480;            // 2621440 f
    float* kqv_buf  = wsf + 3153920;           // 1572864 f
    u16* attn_hi    = (u16*)(wsf + 4726784);   // 524288 u16
    u16* wr_hi      = (u16*)(wsf + 4988928);   // 1622016 u16 (both layers)
                                               // end @ 5799936 f = 23.2 MB

    setup_kernel<<<6612, 256, 0, stream>>>(x, src_mask, notdone, h0,
                                           main_w, proj_w, out_w, flags,
                                           bias_buf, out_buf, (size_t)524288,
                                           wr_hi);
    for (int n = 0; n < 2; ++n) {
        const size_t wb = (size_t)n * 811008;
        ConvArgs ga;
        ga.x = x; ga.prev_out = out_buf; ga.h0 = h0; ga.notdone = notdone;
        ga.hoff = (size_t)n * 524288;
        ga.WhiA = wr_hi + wb;          ga.KciA = 192; ga.CoutA = 320;
        ga.WhiB = wr_hi + wb + 552960; ga.KciB = 128; ga.CoutB = 192;
        ga.biasA = main_b; ga.boffA = (long long)n * 320; ga.OutA = gates_buf;
        ga.biasB = proj_b; ga.boffB = (long long)n * 192; ga.OutB = kqv_buf;
        ga.ntA = 10; ga.NMB = 64;
        conv_mfma_kernel<<<1024, 256, 0, stream>>>(ga, flags);

        attn_kernel<<<1024, 64, 0, stream>>>(
            kqv_buf, k0, v0, pos_w, pos_b, bias_buf, flags, attn_hi,
            (size_t)n * 20971520, (size_t)n * 163840, (size_t)n * 320);

        tail_kernel<<<128, 256, 0, stream>>>(
            attn_hi, wr_hi + wb + 774144,
            out_b, x, gates_buf, c0, notdone, ln_w, ln_b, flags,
            out_buf, d_out, (n == 1) ? 1 : 0,
            (long long)n * 64, (size_t)n * 524288, (size_t)n * 4096);
    }
}

// Round 16
// 538.051 us; speedup vs baseline: 1.4969x; 1.0680x over previous
//
#include <hip/hip_runtime.h>
#include <hip/hip_bf16.h>

typedef __hip_bfloat16 bf16;
typedef unsigned short u16;
typedef __attribute__((ext_vector_type(8))) short short8;
typedef __attribute__((ext_vector_type(4))) float f32x4;

#define Bb   128
#define MEMm 40

__device__ __forceinline__ float LD(const void* p, size_t i, int f32) {
    return f32 ? ((const float*)p)[i] : __bfloat162float(((const bf16*)p)[i]);
}
__device__ __forceinline__ float S2F(short s) {
    u16 u = (u16)s;
    return __bfloat162float(*(bf16*)&u);
}
__device__ __forceinline__ u16 F2S(float v) {
    bf16 h = __float2bfloat16(v);
    return *(u16*)&h;
}
__device__ __forceinline__ int LDB(const void* p, int i, int isbyte) {
    return isbyte ? (int)((const unsigned char*)p)[i] : ((const int*)p)[i];
}

// fused setup. Units: [0,20) bias, [20,276) init_prevout, [276,6612) repack.
__global__ void setup_kernel(const void* __restrict__ x,
                             const void* __restrict__ src_mask,
                             const void* __restrict__ notdone,
                             const void* __restrict__ h0,
                             const void* __restrict__ mw,
                             const void* __restrict__ pw,
                             const void* __restrict__ ow,
                             int* __restrict__ flags,
                             float* __restrict__ biasb,
                             float* __restrict__ outb, size_t hoff,
                             u16* __restrict__ whi) {
    __shared__ int det[3];
    const int bid = blockIdx.x, t = threadIdx.x;
    if (t < 3) det[t] = 0;
    __syncthreads();
    {
        const bf16* xb = (const bf16*)x;
        int bad = 0;
        for (int i = t; i < 4096; i += 256) {
            float v = __bfloat162float(xb[2 * i]);   // even halves: garbage iff f32
            if (!(fabsf(v) < 1e4f)) bad = 1;
        }
        if (bad) atomicOr(&det[0], 1);
        int mb = 0;
        const unsigned* mi = (const unsigned*)src_mask;
        for (int i = t; i < 1280; i += 256) if (mi[i] > 1u) mb = 1;
        if (mb) atomicOr(&det[1], 1);
        int nb = 0;
        const unsigned* ni = (const unsigned*)notdone;
        for (int i = t; i < 32; i += 256) if (ni[i] > 1u) nb = 1;
        if (nb) atomicOr(&det[2], 1);
    }
    __syncthreads();
    const int isf32 = det[0], mbyte = det[1], ndbyte = det[2];
    if (bid == 0 && t < 3) flags[t] = det[t];

    if (bid < 20) {
        int idx = bid * 256 + t;
        if (idx >= Bb * MEMm) return;
        int b = idx / MEMm, m = idx - b * MEMm;
        float v;
        if (m == MEMm - 1) v = 3.0f;
        else {
            bool masked = (LDB(src_mask, b * MEMm + m + 1, mbyte) != 0) ||
                          (LDB(notdone, b, ndbyte) == 0);
            v = masked ? -1e9f : 0.f;
        }
        biasb[idx] = v;
    } else if (bid < 276) {
        int idx = (bid - 20) * 256 + t;      // < 65536
        int b = idx >> 9;
        float nd = (LDB(notdone, b, ndbyte) != 0) ? 1.f : 0.f;
        size_t e = (size_t)idx * 8;
        float v[8];
        if (isf32) {
            const float* hp = (const float*)h0 + hoff + e;
            f32x4 p0 = *(const f32x4*)hp, p1 = *(const f32x4*)(hp + 4);
#pragma unroll
            for (int j = 0; j < 4; ++j) { v[j] = p0[j]; v[4 + j] = p1[j]; }
        } else {
            short8 s = *(const short8*)((const bf16*)h0 + hoff + e);
#pragma unroll
            for (int j = 0; j < 8; ++j) v[j] = S2F(s[j]);
        }
#pragma unroll
        for (int j = 0; j < 8; ++j) outb[e + j] = v[j] * nd;
    } else {
        int gi = (bid - 276) * 256 + t;
        if (gi >= 1622016) return;
        int layer = (gi >= 811008) ? 1 : 0;
        int i = gi - layer * 811008;
        float v;
        if (i < 552960) {
            int blk = i >> 9, r = i & 511;
            int l = r >> 3, j = r & 7;
            int nn = blk & 1, b2 = blk >> 1;
            int s = b2 % 10, tk = b2 / 10;
            int kc = tk % 6, tap = tk / 6;
            int co = s * 32 + nn * 16 + (l & 15);
            int ci = kc * 32 + ((l >> 4) << 3) + j;
            v = LD(mw, (size_t)layer * 552960 + ((size_t)co * 192 + ci) * 9 + tap, isf32);
        } else if (i < 774144) {
            int j2 = i - 552960;
            int blk = j2 >> 9, r = j2 & 511;
            int l = r >> 3, j = r & 7;
            int nn = blk & 1, b2 = blk >> 1;
            int s = b2 % 6, tk = b2 / 6;
            int kc = tk & 3, tap = tk >> 2;
            int co = s * 32 + nn * 16 + (l & 15);
            int ci = kc * 32 + ((l >> 4) << 3) + j;
            v = LD(pw, (size_t)layer * 221184 + ((size_t)co * 128 + ci) * 9 + tap, isf32);
        } else {
            int j2 = i - 774144;
            int tap = j2 / 4096, r = j2 - tap * 4096, co = r / 64, ci = r - co * 64;
            v = LD(ow, (size_t)layer * 36864 + ((size_t)co * 64 + ci) * 9 + tap, isf32);
        }
        whi[gi] = F2S(v);
    }
}

// ---------------------------------------------------------------- MFMA conv
// 9-tap implicit GEMM, pure bf16 operands (f32 accumulate). 1 MFMA per
// fragment pair. block: 4 waves = 2 batches x one 32-co strip. Grid 1024.
struct ConvArgs {
    const void *x; const float *prev_out; const void *h0; const void *notdone;
    const u16 *WhiA, *WhiB;          // fragment-order regions (bf16)
    const void *biasA, *biasB;
    float *OutA, *OutB;              // [B][Cout][64]
    long long boffA, boffB;
    size_t hoff;
    int KciA, KciB, CoutA, CoutB, ntA, NMB;
};

__global__ __launch_bounds__(256) void conv_mfma_kernel(ConvArgs g,
                                                        const int* __restrict__ flags) {
    __shared__ __align__(16) u16 Alds[2][2600];   // [bpair][row*40+ci], row 64 = zeros
    const int t = threadIdx.x, w = t >> 6, lane = t & 63;
    const int bpair = w >> 1, half = w & 1;
    const int bx = blockIdx.x;
    const int mblk = bx % g.NMB, strip = bx / g.NMB;   // strip in [0,16)
    const bool isA = (strip < g.ntA);
    const u16* Whi = isA ? g.WhiA : g.WhiB;
    const int Kci  = isA ? g.KciA : g.KciB;
    const int CoutT= isA ? g.CoutA : g.CoutB;
    float* Out     = isA ? g.OutA : g.OutB;
    const void* bias = isA ? g.biasA : g.biasB;
    const long long boff = isA ? g.boffA : g.boffB;
    const int s = isA ? strip : strip - g.ntA;         // type-local 32-co strip
    const int b = mblk * 2 + bpair;
    const int kcN = Kci >> 5;
    const int CoutT32 = CoutT >> 5;
    const int NITER = kcN * 9;
    const int isf32 = flags[0];
    const float nd = (LDB(g.notdone, b, flags[2]) != 0) ? 1.f : 0.f;

    if (half == 0 && lane < 40) Alds[bpair][2560 + lane] = 0;

    f32x4 acc[4];
#pragma unroll
    for (int i = 0; i < 4; ++i) { f32x4 z = {0.f, 0.f, 0.f, 0.f}; acc[i] = z; }

    auto wbase = [&](int it) -> size_t {
        int kc = it / 9, tap = it - kc * 9;
        return ((size_t)((tap * kcN + kc) * CoutT32 + s) * 2 + half) * 512 + (size_t)lane * 8;
    };

    short8 wcur = *(const short8*)(Whi + wbase(0));
    short8 wnext = wcur;

    for (int it = 0; it < NITER; ++it) {
        const int kc = it / 9, tap = it - kc * 9;
        if (it + 1 < NITER) wnext = *(const short8*)(Whi + wbase(it + 1));
        if (tap == 0) {
            __syncthreads();   // WAR: prior kc's A reads complete
            const int px = lane;
            const int c0i = half * 16;
            const int cbase = kc * 32;
            short8 hA, hB;
#pragma unroll
            for (int cl2 = 0; cl2 < 16; ++cl2) {
                int c = cbase + c0i + cl2;
                float v;
                if (c < 64) {
                    size_t o = (size_t)b * 4096 + (size_t)c * 64 + px;
                    v = isf32 ? ((const float*)g.x)[o] : S2F(((const short*)g.x)[o]);
                } else if (c < 128) {
                    v = g.prev_out[(size_t)b * 4096 + (size_t)(c - 64) * 64 + px];
                } else {
                    size_t o = g.hoff + (size_t)b * 4096 + (size_t)(c - 128) * 64 + px;
                    v = (isf32 ? ((const float*)g.h0)[o] : S2F(((const short*)g.h0)[o])) * nd;
                }
                u16 hh = F2S(v);
                if (cl2 < 8) hA[cl2] = (short)hh;
                else         hB[cl2 - 8] = (short)hh;
            }
            *(short8*)&Alds[bpair][px * 40 + c0i]     = hA;
            *(short8*)&Alds[bpair][px * 40 + c0i + 8] = hB;
            __syncthreads();   // RAW: A visible to both waves of the pair
        }
        const int dy = tap / 3 - 1, dx = tap % 3 - 1;
        const int q8 = (lane >> 4) * 8;
        const int ml = lane & 15;
        short8 aH[4];
#pragma unroll
        for (int mt = 0; mt < 4; ++mt) {
            int px = mt * 16 + ml;
            int yy = (px >> 3) + dy, xx = (px & 7) + dx;
            int row = ((unsigned)yy < 8u && (unsigned)xx < 8u) ? yy * 8 + xx : 64;
            aH[mt] = *(const short8*)&Alds[bpair][row * 40 + q8];
        }
#pragma unroll
        for (int mt = 0; mt < 4; ++mt)
            acc[mt] = __builtin_amdgcn_mfma_f32_16x16x32_bf16(aH[mt], wcur, acc[mt], 0, 0, 0);
        wcur = wnext;
    }
    // epilogue: C layout col=lane&15, row=(lane>>4)*4+reg
    const int q = lane >> 4, ml = lane & 15;
    {
        int co = s * 32 + half * 16 + ml;
        float bv = LD(bias, (size_t)boff + co, isf32);
#pragma unroll
        for (int mt = 0; mt < 4; ++mt) {
            f32x4 v = acc[mt];
            v[0] += bv; v[1] += bv; v[2] += bv; v[3] += bv;
            *(f32x4*)&Out[((size_t)b * CoutT + co) * 64 + mt * 16 + q * 4] = v;
        }
    }
}

// ---------------------------------------------------------------- attention
// r13 structure widened to 8 waves/unit (512 thr): each wave does 5 m-rows
// (m = wid + i*8), full-depth ILP, V loads issued before softmax barrier.
// 8192 waves total = 32/CU (occupancy cap).
__global__ __launch_bounds__(512) void attn_kernel(
    const float* __restrict__ kqv,
    const void* __restrict__ k0,
    const void* __restrict__ v0,
    const void* __restrict__ pw,
    const void* __restrict__ pb,
    const float* __restrict__ biasb,
    const int* __restrict__ flags,
    u16* __restrict__ ahi,
    size_t kvoff, size_t pwoff, size_t pboff) {
    __shared__ float qv[512], kl[512], vl[512], sc[40], wexp[40];
    __shared__ float accbuf[8][512];
    const int t = threadIdx.x;
    const int isf32 = flags[0];
    const int b = blockIdx.x >> 3, h = blockIdx.x & 7;
    const size_t kqb = (size_t)b * 192 * 64;
    for (int d = t; d < 512; d += 512) {
        int hd = d >> 6, ss = d & 63;
        qv[d] = kqv[kqb + (h * 24 + 8 + hd) * 64 + ss] * 0.044194173824159216f;
        kl[d] = kqv[kqb + (h * 24 + 0 + hd) * 64 + ss];
        vl[d] = kqv[kqb + (h * 24 + 16 + hd) * 64 + ss];
    }
    __syncthreads();
    const int wid = t >> 6, lane = t & 63;
    const int d0 = lane * 8;
    const size_t kvbase = kvoff + ((size_t)(b * 8 + h)) * (size_t)(40 * 512);

    float q8[8];
#pragma unroll
    for (int j = 0; j < 8; ++j) q8[j] = qv[d0 + j];

    if (!isf32) {
        const bf16* kp = (const bf16*)k0;
        const bf16* pp = (const bf16*)pw;
        const bf16* vp = (const bf16*)v0;
        short8 kr[5], pr[5];
#pragma unroll
        for (int i = 0; i < 5; ++i) {
            int m = wid + i * 8;
            pr[i] = *(const short8*)(pp + pwoff + (size_t)m * 4096 + h * 512 + d0);
            if (m < 39)
                kr[i] = *(const short8*)(kp + kvbase + (size_t)(m + 1) * 512 + d0);
        }
#pragma unroll
        for (int i = 0; i < 5; ++i) {
            int m = wid + i * 8;
            float p = 0.f;
            if (m < 39) {
#pragma unroll
                for (int j = 0; j < 8; ++j)
                    p += q8[j] * (S2F(kr[i][j]) + S2F(pr[i][j]));
            } else {
#pragma unroll
                for (int j = 0; j < 8; ++j)
                    p += q8[j] * (kl[d0 + j] + S2F(pr[i][j]));
            }
#pragma unroll
            for (int off = 32; off > 0; off >>= 1) p += __shfl_down(p, off, 64);
            if (lane == 0)
                sc[m] = p + biasb[b * 40 + m] + LD(pb, pboff + m * 8 + h, 0);
        }
        short8 vr[5];
#pragma unroll
        for (int i = 0; i < 5; ++i) {
            int m = wid + i * 8;
            if (m < 39)
                vr[i] = *(const short8*)(vp + kvbase + (size_t)(m + 1) * 512 + d0);
        }
        __syncthreads();
        float mx = -1e30f;
        for (int m = 0; m < 40; ++m) mx = fmaxf(mx, sc[m]);
        if (t < 40) wexp[t] = __expf(sc[t] - mx);
        __syncthreads();
        float sum = 0.f;
        for (int m = 0; m < 40; ++m) sum += wexp[m];
        float rs = 1.f / sum;
        float acc8[8];
#pragma unroll
        for (int j = 0; j < 8; ++j) acc8[j] = 0.f;
#pragma unroll
        for (int i = 0; i < 5; ++i) {
            int m = wid + i * 8;
            float wgt = wexp[m];
            if (m < 39) {
#pragma unroll
                for (int j = 0; j < 8; ++j) acc8[j] += wgt * S2F(vr[i][j]);
            } else {
#pragma unroll
                for (int j = 0; j < 8; ++j) acc8[j] += wgt * vl[d0 + j];
            }
        }
#pragma unroll
        for (int j = 0; j < 8; ++j) accbuf[wid][d0 + j] = acc8[j];
        __syncthreads();
        for (int d = t; d < 512; d += 512) {
            float acc = ((accbuf[0][d] + accbuf[1][d]) + (accbuf[2][d] + accbuf[3][d]))
                      + ((accbuf[4][d] + accbuf[5][d]) + (accbuf[6][d] + accbuf[7][d]));
            acc *= rs;
            int ch = h * 8 + (d >> 6), px = d & 63;
            ahi[(size_t)b * 4096 + px * 64 + ch] = F2S(acc);
        }
        return;
    }

    // ---- f32 fallback path (correctness-only)
    for (int m = wid; m < 40; m += 8) {
        float kc[8];
        if (m < 39) {
            const float* kp = (const float*)k0 + kvbase + (size_t)(m + 1) * 512 + d0;
            f32x4 p0 = *(const f32x4*)kp, p1 = *(const f32x4*)(kp + 4);
#pragma unroll
            for (int j = 0; j < 4; ++j) { kc[j] = p0[j]; kc[4 + j] = p1[j]; }
        } else {
#pragma unroll
            for (int j = 0; j < 8; ++j) kc[j] = kl[d0 + j];
        }
        const float* pp = (const float*)pw + pwoff + (size_t)m * 4096 + h * 512 + d0;
        f32x4 p0 = *(const f32x4*)pp, p1 = *(const f32x4*)(pp + 4);
#pragma unroll
        for (int j = 0; j < 4; ++j) { kc[j] += p0[j]; kc[4 + j] += p1[j]; }
        float p = 0.f;
#pragma unroll
        for (int j = 0; j < 8; ++j) p += q8[j] * kc[j];
#pragma unroll
        for (int off = 32; off > 0; off >>= 1) p += __shfl_down(p, off, 64);
        if (lane == 0)
            sc[m] = p + biasb[b * 40 + m] + LD(pb, pboff + m * 8 + h, 1);
    }
    __syncthreads();
    float mx = -1e30f;
    for (int m = 0; m < 40; ++m) mx = fmaxf(mx, sc[m]);
    if (t < 40) wexp[t] = __expf(sc[t] - mx);
    __syncthreads();
    float sum = 0.f;
    for (int m = 0; m < 40; ++m) sum += wexp[m];
    float rs = 1.f / sum;
    float acc8[8];
#pragma unroll
    for (int j = 0; j < 8; ++j) acc8[j] = 0.f;
    for (int m = wid; m < 40; m += 8) {
        float wgt = wexp[m];
        if (m < 39) {
            const float* vp = (const float*)v0 + kvbase + (size_t)(m + 1) * 512 + d0;
            f32x4 p0 = *(const f32x4*)vp, p1 = *(const f32x4*)(vp + 4);
#pragma unroll
            for (int j = 0; j < 4; ++j) { acc8[j] += wgt * p0[j]; acc8[4 + j] += wgt * p1[j]; }
        } else {
#pragma unroll
            for (int j = 0; j < 8; ++j) acc8[j] += wgt * vl[d0 + j];
        }
    }
#pragma unroll
    for (int j = 0; j < 8; ++j) accbuf[wid][d0 + j] = acc8[j];
    __syncthreads();
    for (int d = t; d < 512; d += 512) {
        float acc = ((accbuf[0][d] + accbuf[1][d]) + (accbuf[2][d] + accbuf[3][d]))
                  + ((accbuf[4][d] + accbuf[5][d]) + (accbuf[6][d] + accbuf[7][d]));
        acc *= rs;
        int ch = h * 8 + (d >> 6), px = d & 63;
        ahi[(size_t)b * 4096 + px * 64 + ch] = F2S(acc);
    }
}

// ---------------------------------------------------------------- tail
// fused out-conv (pure bf16 MFMA, OLD W layout) + residual + LN + LSTM.
__global__ __launch_bounds__(256) void tail_kernel(
    const u16* __restrict__ ahi,
    const u16* __restrict__ whi,
    const void* __restrict__ outb_bias,
    const void* __restrict__ x,
    const float* __restrict__ gates,
    const void* __restrict__ c0,
    const void* __restrict__ notdone,
    const void* __restrict__ lnw, const void* __restrict__ lnb,
    const int* __restrict__ flags,
    float* __restrict__ out_buf, void* __restrict__ dout, int write_out,
    long long boff, size_t coff, size_t lnoff) {
    __shared__ __align__(16) u16 Ald[2][2600];       // [kc][px*40+cl], row 64 zeros
    __shared__ __align__(16) u16 Wl[2][2560];        // [par][co*40+ci]
    __shared__ float red[8], stats[2];
    const int t = threadIdx.x, w = t >> 6, lane = t & 63;
    const int b = blockIdx.x;
    const int isf32 = flags[0], ndbyte = flags[2];

    {
        int px = t >> 2, ci16 = (t & 3) * 16;
        int chunk = ci16 >> 5, cl = ci16 & 31;
        size_t o = ((size_t)b * 64 + px) * 64 + ci16;
        *(uint4*)&Ald[chunk][px * 40 + cl]     = *(const uint4*)(ahi + o);
        *(uint4*)&Ald[chunk][px * 40 + cl + 8] = *(const uint4*)(ahi + o + 8);
        if (t < 80) { int ch = t / 40, i = t % 40; Ald[ch][2560 + i] = 0; }
    }

    const int co_l = t >> 2, jj = t & 3;
    uint4 hv;
    auto issueW = [&](int it) {
        int kc = it / 9, tap = it - kc * 9;
        size_t o = ((size_t)(tap * 64 + co_l)) * 64 + kc * 32 + jj * 8;
        hv = *(const uint4*)(whi + o);
    };

    f32x4 acc[4];
#pragma unroll
    for (int i = 0; i < 4; ++i) { f32x4 z = {0.f, 0.f, 0.f, 0.f}; acc[i] = z; }

    issueW(0);
    for (int it = 0; it < 18; ++it) {
        const int kc = it / 9, tap = it - kc * 9;
        const int par = it & 1;
        *(uint4*)&Wl[par][co_l * 40 + jj * 8] = hv;
        __syncthreads();
        if (it + 1 < 18) issueW(it + 1);
        const int dy = tap / 3 - 1, dx = tap % 3 - 1;
        const int q8 = (lane >> 4) * 8;
        const int ml = lane & 15;
        short8 aH[4];
#pragma unroll
        for (int mt = 0; mt < 4; ++mt) {
            int px = mt * 16 + ml;
            int yy = (px >> 3) + dy, xx = (px & 7) + dx;
            int row = ((unsigned)yy < 8u && (unsigned)xx < 8u) ? yy * 8 + xx : 64;
            aH[mt] = *(const short8*)&Ald[kc][row * 40 + q8];
        }
        short8 bH = *(const short8*)&Wl[par][(w * 16 + ml) * 40 + q8];
#pragma unroll
        for (int mt = 0; mt < 4; ++mt)
            acc[mt] = __builtin_amdgcn_mfma_f32_16x16x32_bf16(aH[mt], bH, acc[mt], 0, 0, 0);
    }

    // epilogue: thread holds 16 values at co = w*16+(lane&15), px = mt*16+(lane>>4)*4+r
    const int q = lane >> 4, ml = lane & 15;
    const int co = w * 16 + ml;
    const size_t base = (size_t)b * 4096;
    float bv = LD(outb_bias, (size_t)boff + co, isf32);
    float vals[16];
    float sum = 0.f, sumsq = 0.f;
#pragma unroll
    for (int mt = 0; mt < 4; ++mt) {
        int px0 = mt * 16 + q * 4;
#pragma unroll
        for (int r = 0; r < 4; ++r) {
            float xv = LD(x, base + (size_t)co * 64 + px0 + r, isf32);
            float val = acc[mt][r] + bv + xv;
            vals[mt * 4 + r] = val; sum += val; sumsq += val * val;
        }
    }
#pragma unroll
    for (int off = 32; off > 0; off >>= 1) {
        sum   += __shfl_down(sum, off, 64);
        sumsq += __shfl_down(sumsq, off, 64);
    }
    if (lane == 0) { red[w] = sum; red[4 + w] = sumsq; }
    __syncthreads();
    if (t == 0) {
        float ts = red[0] + red[1] + red[2] + red[3];
        float tq = red[4] + red[5] + red[6] + red[7];
        float mu = ts * (1.f / 4096.f);
        float var = tq * (1.f / 4096.f) - mu * mu;
        stats[0] = mu; stats[1] = rsqrtf(fmaxf(var, 0.f) + 1e-5f);
    }
    __syncthreads();
    const float mu = stats[0], rstd = stats[1];
    const float nd = (LDB(notdone, b, ndbyte) != 0) ? 1.f : 0.f;
    const size_t gbase = (size_t)b * 320 * 64;
#pragma unroll
    for (int mt = 0; mt < 4; ++mt) {
        int px0 = mt * 16 + q * 4;
        size_t i0 = (size_t)co * 64 + px0;
        f32x4 gi4 = *(const f32x4*)&gates[gbase + (size_t)(co      ) * 64 + px0];
        f32x4 gf4 = *(const f32x4*)&gates[gbase + (size_t)(co +  64) * 64 + px0];
        f32x4 go4 = *(const f32x4*)&gates[gbase + (size_t)(co + 128) * 64 + px0];
        f32x4 gg4 = *(const f32x4*)&gates[gbase + (size_t)(co + 192) * 64 + px0];
        f32x4 ga4 = *(const f32x4*)&gates[gbase + (size_t)(co + 256) * 64 + px0];
        f32x4 ov;
#pragma unroll
        for (int r = 0; r < 4; ++r) {
            size_t i = i0 + r;
            float aon = (vals[mt * 4 + r] - mu) * rstd * LD(lnw, lnoff + i, isf32)
                        + LD(lnb, lnoff + i, isf32);
            float gi = 1.f / (1.f + __expf(-gi4[r]));
            float gf = 1.f / (1.f + __expf(-gf4[r]));
            float go = 1.f / (1.f + __expf(-go4[r]));
            float gg = tanhf(gg4[r]);
            float ga = 1.f / (1.f + __expf(-ga4[r]));
            float cc = LD(c0, coff + base + i, isf32) * nd;
            float cn = gf * cc + gi * gg + ga * tanhf(aon);
            float o  = go * tanhf(cn);
            ov[r] = o;
            if (write_out) {
                if (isf32) ((float*)dout)[base + i] = o;
                else       ((bf16*)dout)[base + i] = __float2bfloat16(o);
            }
        }
        *(f32x4*)&out_buf[base + i0] = ov;
    }
}

extern "C" void kernel_launch(void* const* d_in, const int* in_sizes, int n_in,
                              void* d_out, int out_size, void* d_ws, size_t ws_size,
                              hipStream_t stream) {
    const void* x      = d_in[0];
    const void* h0     = d_in[1];
    const void* c0     = d_in[2];
    const void* k0     = d_in[3];
    const void* v0     = d_in[4];
    const void* src_mask = d_in[5];
    const void* notdone  = d_in[6];
    const void* main_w = d_in[7];
    const void* main_b = d_in[8];
    const void* proj_w = d_in[9];
    const void* proj_b = d_in[10];
    const void* out_w  = d_in[11];
    const void* out_b  = d_in[12];
    const void* ln_w   = d_in[13];
    const void* ln_b   = d_in[14];
    const void* pos_w  = d_in[15];
    const void* pos_b  = d_in[16];

    float* wsf = (float*)d_ws;
    int*   flags    = (int*)d_ws;
    float* bias_buf = wsf + 8;
    float* out_buf  = wsf + 8192;              // 524288 f
    float* gates_buf= wsf + 532480;            // 2621440 f
    float* kqv_buf  = wsf + 3153920;           // 1572864 f
    u16* attn_hi    = (u16*)(wsf + 4726784);   // 524288 u16
    u16* wr_hi      = (u16*)(wsf + 4988928);   // 1622016 u16 (both layers)
                                               // end @ 5799936 f = 23.2 MB

    setup_kernel<<<6612, 256, 0, stream>>>(x, src_mask, notdone, h0,
                                           main_w, proj_w, out_w, flags,
                                           bias_buf, out_buf, (size_t)524288,
                                           wr_hi);
    for (int n = 0; n < 2; ++n) {
        const size_t wb = (size_t)n * 811008;
        ConvArgs ga;
        ga.x = x; ga.prev_out = out_buf; ga.h0 = h0; ga.notdone = notdone;
        ga.hoff = (size_t)n * 524288;
        ga.WhiA = wr_hi + wb;          ga.KciA = 192; ga.CoutA = 320;
        ga.WhiB = wr_hi + wb + 552960; ga.KciB = 128; ga.CoutB = 192;
        ga.biasA = main_b; ga.boffA = (long long)n * 320; ga.OutA = gates_buf;
        ga.biasB = proj_b; ga.boffB = (long long)n * 192; ga.OutB = kqv_buf;
        ga.ntA = 10; ga.NMB = 64;
        conv_mfma_kernel<<<1024, 256, 0, stream>>>(ga, flags);

        attn_kernel<<<1024, 512, 0, stream>>>(
            kqv_buf, k0, v0, pos_w, pos_b, bias_buf, flags, attn_hi,
            (size_t)n * 20971520, (size_t)n * 163840, (size_t)n * 320);

        tail_kernel<<<128, 256, 0, stream>>>(
            attn_hi, wr_hi + wb + 774144,
            out_b, x, gates_buf, c0, notdone, ln_w, ln_b, flags,
            out_buf, d_out, (n == 1) ? 1 : 0,
            (long long)n * 64, (size_t)n * 524288, (size_t)n * 4096);
    }
}